// Round 1
// baseline (3926.615 us; speedup 1.0000x reference)
//
#include <hip/hip_runtime.h>
#include <math.h>

#define T_STEPS 2048
#define BATCH   128
#define HID     128
#define G4      512   // 4*H

__device__ __forceinline__ float fast_sig(float x) {
    return __fdividef(1.0f, 1.0f + __expf(-x));
}
__device__ __forceinline__ float fast_tanh(float x) {
    // 2*sigmoid(2x)-1 ; saturates correctly at +/-inf
    return fmaf(2.0f, __fdividef(1.0f, 1.0f + __expf(-2.0f * x)), -1.0f);
}

// ---------------------------------------------------------------------------
// Recurrent LSTM layer for the single live batch element (b = 127).
// 1 workgroup, 512 threads. Thread j owns gate-row j: Whh row j lives in
// 32 float4 VGPRs (128 regs). h state broadcast through LDS (same-address
// float4 reads = bank-conflict-free broadcast). Activations are computed by
// the thread that produced the gate (spread across all 8 waves); only the
// c/h combine (+1 tanh) runs on the 2-wave tail.
// IS_L0: pre-activation = bias + x[t,127]*Wih0[j]. else: pre = G[t*512+j]
// (bias already folded in by the GEMM).
// ---------------------------------------------------------------------------
template<bool IS_L0>
__global__ __launch_bounds__(512, 2)
void lstm_rec_kernel(const float* __restrict__ Wrec,   // (512,128) Whh, row-major
                     const float* __restrict__ xin,    // L0: x (T,B) ; L1: G (T,512)
                     const float* __restrict__ wih0,   // L0 only: (512,)
                     const float* __restrict__ bih,    // L0 only
                     const float* __restrict__ bhh,    // L0 only
                     float* __restrict__ hout)         // (T,128)
{
    const int j = threadIdx.x;

    __shared__ float4 h4_lds[HID / 4];
    __shared__ float  g_lds[G4];
    float* h_lds = reinterpret_cast<float*>(h4_lds);

    // weights: row j of Whh, 128 floats in registers
    float4 w[32];
    const float4* wrow = reinterpret_cast<const float4*>(Wrec + (size_t)j * HID);
    #pragma unroll
    for (int i = 0; i < 32; ++i) w[i] = wrow[i];

    float bj = 0.0f, wj = 0.0f;
    if (IS_L0) { bj = bih[j] + bhh[j]; wj = wih0[j]; }

    float c_reg = 0.0f;
    if (j < HID) h_lds[j] = 0.0f;
    __syncthreads();

    // software-pipelined input prefetch (hides global load latency behind dot)
    float pre_next;
    if (IS_L0) pre_next = fmaf(xin[BATCH - 1], wj, bj);
    else       pre_next = xin[j];

    for (int t = 0; t < T_STEPS; ++t) {
        float pre = pre_next;
        if (t + 1 < T_STEPS) {
            if (IS_L0) pre_next = fmaf(xin[(size_t)(t + 1) * BATCH + (BATCH - 1)], wj, bj);
            else       pre_next = xin[(size_t)(t + 1) * G4 + j];
        }

        // dot(h, Whh_row_j): 32 float4 LDS broadcasts, 4 accumulator chains
        float a0 = 0.f, a1 = 0.f, a2 = 0.f, a3 = 0.f;
        #pragma unroll
        for (int i = 0; i < 32; ++i) {
            float4 hv = h4_lds[i];
            a0 = fmaf(hv.x, w[i].x, a0);
            a1 = fmaf(hv.y, w[i].y, a1);
            a2 = fmaf(hv.z, w[i].z, a2);
            a3 = fmaf(hv.w, w[i].w, a3);
        }
        float g = pre + ((a0 + a1) + (a2 + a3));

        // distributed activation: gate 0(i),1(f),3(o) -> sigmoid ; gate 2(g) -> tanh
        const int gate = j >> 7;                       // wave-uniform branch
        float act = (gate == 2) ? fast_tanh(g) : fast_sig(g);
        g_lds[j] = act;
        __syncthreads();

        if (j < HID) {
            float ai = g_lds[j];
            float af = g_lds[j + 128];
            float ag = g_lds[j + 256];
            float ao = g_lds[j + 384];
            c_reg = fmaf(af, c_reg, ai * ag);
            float h = ao * fast_tanh(c_reg);
            h_lds[j] = h;
            hout[(size_t)t * HID + j] = h;
        }
        __syncthreads();
    }
}

// ---------------------------------------------------------------------------
// C[m,n] = sum_k A[m,k] * W[n,k] + b1[n] (+ b2[n])    K = 128 fixed
// 64x64 tiles, 256 threads, 4x4 micro-tile per thread, k-major LDS layout.
// ---------------------------------------------------------------------------
#define BM 64
#define BN 64
__global__ __launch_bounds__(256)
void gemm_bias_kernel(const float* __restrict__ A,   // (M,128)
                      const float* __restrict__ W,   // (N,128)
                      const float* __restrict__ b1,
                      const float* __restrict__ b2,  // may be null
                      float* __restrict__ C,         // (M,N)
                      int M, int N)
{
    __shared__ float Al[128][BM + 4];
    __shared__ float Wl[128][BN + 4];
    const int tid    = threadIdx.x;
    const int m_base = blockIdx.x * BM;
    const int n_base = blockIdx.y * BN;

    {
        const int r  = tid >> 2;          // 0..63
        const int kq = (tid & 3) * 32;    // 0,32,64,96
        const float4* srcA = reinterpret_cast<const float4*>(A + (size_t)(m_base + r) * 128 + kq);
        #pragma unroll
        for (int i = 0; i < 8; ++i) {
            float4 v = srcA[i];
            int k = kq + 4 * i;
            Al[k + 0][r] = v.x; Al[k + 1][r] = v.y; Al[k + 2][r] = v.z; Al[k + 3][r] = v.w;
        }
        const float4* srcW = reinterpret_cast<const float4*>(W + (size_t)(n_base + r) * 128 + kq);
        #pragma unroll
        for (int i = 0; i < 8; ++i) {
            float4 v = srcW[i];
            int k = kq + 4 * i;
            Wl[k + 0][r] = v.x; Wl[k + 1][r] = v.y; Wl[k + 2][r] = v.z; Wl[k + 3][r] = v.w;
        }
    }
    __syncthreads();

    const int tm = (tid & 15) * 4;
    const int tn = (tid >> 4) * 4;
    float acc[4][4] = {};
    #pragma unroll 8
    for (int k = 0; k < 128; ++k) {
        float4 av = *reinterpret_cast<const float4*>(&Al[k][tm]);
        float4 wv = *reinterpret_cast<const float4*>(&Wl[k][tn]);
        acc[0][0] = fmaf(av.x, wv.x, acc[0][0]);
        acc[0][1] = fmaf(av.x, wv.y, acc[0][1]);
        acc[0][2] = fmaf(av.x, wv.z, acc[0][2]);
        acc[0][3] = fmaf(av.x, wv.w, acc[0][3]);
        acc[1][0] = fmaf(av.y, wv.x, acc[1][0]);
        acc[1][1] = fmaf(av.y, wv.y, acc[1][1]);
        acc[1][2] = fmaf(av.y, wv.z, acc[1][2]);
        acc[1][3] = fmaf(av.y, wv.w, acc[1][3]);
        acc[2][0] = fmaf(av.z, wv.x, acc[2][0]);
        acc[2][1] = fmaf(av.z, wv.y, acc[2][1]);
        acc[2][2] = fmaf(av.z, wv.z, acc[2][2]);
        acc[2][3] = fmaf(av.z, wv.w, acc[2][3]);
        acc[3][0] = fmaf(av.w, wv.x, acc[3][0]);
        acc[3][1] = fmaf(av.w, wv.y, acc[3][1]);
        acc[3][2] = fmaf(av.w, wv.z, acc[3][2]);
        acc[3][3] = fmaf(av.w, wv.w, acc[3][3]);
    }

    float bias[4];
    #pragma unroll
    for (int i = 0; i < 4; ++i) {
        int n = n_base + tn + i;
        bias[i] = b1[n] + (b2 ? b2[n] : 0.0f);
    }
    #pragma unroll
    for (int mi = 0; mi < 4; ++mi) {
        float4 o;
        o.x = acc[mi][0] + bias[0];
        o.y = acc[mi][1] + bias[1];
        o.z = acc[mi][2] + bias[2];
        o.w = acc[mi][3] + bias[3];
        *reinterpret_cast<float4*>(C + (size_t)(m_base + tm + mi) * N + n_base + tn) = o;
    }
}

// ---------------------------------------------------------------------------
// BatchNorm stats over the T axis (2048 rows) per column (128 cols).
// scale = gamma * rsqrt(var + eps) ; shift = beta - mean * scale
// ---------------------------------------------------------------------------
__global__ __launch_bounds__(512)
void bn_stats_kernel(const float* __restrict__ Z,       // (T,128)
                     const float* __restrict__ gamma,
                     const float* __restrict__ beta,
                     float* __restrict__ scale,
                     float* __restrict__ shift)
{
    const int tid = threadIdx.x;
    const int col = tid & 127;
    const int seg = tid >> 7;     // 0..3
    float s = 0.f, sq = 0.f;
    for (int t = seg * 512; t < (seg + 1) * 512; ++t) {
        float v = Z[(size_t)t * 128 + col];
        s += v;
        sq = fmaf(v, v, sq);
    }
    __shared__ float ps[4][128], pq[4][128];
    ps[seg][col] = s;
    pq[seg][col] = sq;
    __syncthreads();
    if (tid < 128) {
        float sum = ps[0][tid] + ps[1][tid] + ps[2][tid] + ps[3][tid];
        float sqq = pq[0][tid] + pq[1][tid] + pq[2][tid] + pq[3][tid];
        float mean = sum * (1.0f / 2048.0f);
        float var  = sqq * (1.0f / 2048.0f) - mean * mean;
        float sc = gamma[tid] * rsqrtf(var + 1e-5f);
        scale[tid] = sc;
        shift[tid] = beta[tid] - mean * sc;
    }
}

// ---------------------------------------------------------------------------
// out[t,o] = fc2_b[o] + sum_j relu(Z[t,j]*scale[j]+shift[j]) * fc2_w[o,j]
// 16384 outputs, one per thread.
// ---------------------------------------------------------------------------
__global__ __launch_bounds__(512)
void fc2_kernel(const float* __restrict__ Z,      // (T,128)
                const float* __restrict__ scale,
                const float* __restrict__ shift,
                const float* __restrict__ fc2_w,  // (8,128)
                const float* __restrict__ fc2_b,
                float* __restrict__ out)          // (T,8)
{
    const int gid = blockIdx.x * blockDim.x + threadIdx.x;   // 0..16383
    const int o = gid & 7;
    const int t = gid >> 3;

    __shared__ float w_s[8][132];                 // pad 132: breaks 8-way bank conflict
    __shared__ float sc_s[128], sh_s[128];
    for (int i = threadIdx.x; i < 1024; i += 512) w_s[i >> 7][i & 127] = fc2_w[i];
    if (threadIdx.x < 128) {
        sc_s[threadIdx.x] = scale[threadIdx.x];
        sh_s[threadIdx.x] = shift[threadIdx.x];
    }
    __syncthreads();

    float acc = fc2_b[o];
    const float* zrow = Z + (size_t)t * 128;
    #pragma unroll 4
    for (int k = 0; k < 128; ++k) {
        float zn = fmaf(zrow[k], sc_s[k], sh_s[k]);
        zn = fmaxf(zn, 0.0f);
        acc = fmaf(zn, w_s[o][k], acc);
    }
    out[gid] = acc;
}

// ---------------------------------------------------------------------------
extern "C" void kernel_launch(void* const* d_in, const int* in_sizes, int n_in,
                              void* d_out, int out_size, void* d_ws, size_t ws_size,
                              hipStream_t stream)
{
    const float* x     = (const float*)d_in[0];   // (2048,128,1)
    const float* Wih0  = (const float*)d_in[1];   // (512,1)
    const float* Whh0  = (const float*)d_in[2];   // (512,128)
    const float* bih0  = (const float*)d_in[3];
    const float* bhh0  = (const float*)d_in[4];
    const float* Wih1  = (const float*)d_in[5];   // (512,128)
    const float* Whh1  = (const float*)d_in[6];   // (512,128)
    const float* bih1  = (const float*)d_in[7];
    const float* bhh1  = (const float*)d_in[8];
    const float* fc1_w = (const float*)d_in[9];   // (128,128)
    const float* fc1_b = (const float*)d_in[10];
    const float* gamma = (const float*)d_in[11];
    const float* beta  = (const float*)d_in[12];
    const float* fc2_w = (const float*)d_in[13];  // (8,128)
    const float* fc2_b = (const float*)d_in[14];
    float* out = (float*)d_out;                    // (2048,8) fp32

    // workspace layout (~7.3 MB total)
    float* h1    = (float*)d_ws;            // 2048*128
    float* G     = h1  + T_STEPS * HID;     // 2048*512
    float* h2    = G   + T_STEPS * G4;      // 2048*128
    float* z     = h2  + T_STEPS * HID;     // 2048*128
    float* scale = z   + T_STEPS * HID;     // 128
    float* shift = scale + 128;             // 128

    // K1: layer-0 recurrence (only batch element 127 matters)
    lstm_rec_kernel<true><<<1, 512, 0, stream>>>(Whh0, x, Wih0, bih0, bhh0, h1);

    // K2: layer-1 input GEMM: G[t,:] = h1[t,:] @ Wih1^T + (bih1+bhh1)
    dim3 g2(T_STEPS / BM, G4 / BN);
    gemm_bias_kernel<<<g2, 256, 0, stream>>>(h1, Wih1, bih1, bhh1, G, T_STEPS, G4);

    // K3: layer-1 recurrence consuming precomputed G
    lstm_rec_kernel<false><<<1, 512, 0, stream>>>(Whh1, G, nullptr, nullptr, nullptr, h2);

    // K4a: z = h2 @ fc1^T + fc1_b
    dim3 g4(T_STEPS / BM, HID / BN);
    gemm_bias_kernel<<<g4, 256, 0, stream>>>(h2, fc1_w, fc1_b, nullptr, z, T_STEPS, HID);

    // K4b: batchnorm stats over T axis
    bn_stats_kernel<<<1, 512, 0, stream>>>(z, gamma, beta, scale, shift);

    // K4c: normalize + relu + fc2
    fc2_kernel<<<T_STEPS * 8 / 512, 512, 0, stream>>>(z, scale, shift, fc2_w, fc2_b, out);
}